// Round 2
// baseline (473.051 us; speedup 1.0000x reference)
//
#include <hip/hip_runtime.h>
#include <hip/hip_bf16.h>

// messages[e,:] = edge_matrices[type(e)] @ h_w[e,:]
// Inputs (all FLOAT32 per reference): h_v (unused), h_w (E,128),
// edge_features (E,8) one-hot, edge_matrices (8,128,128) f32. Output f32 (E,128).
//
// Round-2 structure: WAVE-AUTONOMOUS main loop, ZERO barriers after setup.
//   - Per block (chunk=2560, type k): stage M_k into LDS as bf16 (once),
//     ballot-compact the match list. Two __syncthreads total.
//   - Each wave owns whole 16-edge groups (round-robin w, w+4, ...), computes
//     ALL 128 h for its edges. Edge rows are gathered DIRECTLY from global
//     into the MFMA B-fragment layout (lane c = edge, 8 consecutive floats
//     per (q,kk) slice) -- no LDS staging, no transpose, no block sync.
//   - Ping-pong register prefetch (static A/B names) hides HBM gather latency
//     under the previous group's ds_read+MFMA+store phase. Waves never wait
//     on each other -> high memory duty cycle (the round-1 limiter).

#define NEDGES 320000
#define HIDDEN 128
#define CHUNK  2560            // 320000 / 2560 = 125 chunks exactly
#define RS     272             // LDS matrix row stride bytes (256B bf16 + 16 pad)

typedef __bf16 bf16x8 __attribute__((ext_vector_type(8)));
typedef float  f32x4  __attribute__((ext_vector_type(4)));

struct G { float4 v[8]; };     // one group's gathered h_w slice (per lane, 128 B)

__device__ inline bf16x8 pack8(const float4 v0, const float4 v1) {
    bf16x8 p;
    p[0] = (__bf16)v0.x; p[1] = (__bf16)v0.y; p[2] = (__bf16)v0.z; p[3] = (__bf16)v0.w;
    p[4] = (__bf16)v1.x; p[5] = (__bf16)v1.y; p[6] = (__bf16)v1.z; p[7] = (__bf16)v1.w;
    return p;
}

// Gather group [base, base+16) of the match list: lane (q,c) loads edge
// list[base+c]'s floats [kk*32+q*8, +8) for kk=0..3 (2x float4 each).
__device__ inline void gather(const float* __restrict__ h_w,
                              const unsigned short* list, int e0, int n_g,
                              int base, int q, int c, G& g) {
    int idx = base + c;
    if (idx >= n_g) idx = n_g - 1;          // clamp (only last group)
    const float* src = h_w + (size_t)(e0 + list[idx]) * HIDDEN + q * 8;
#pragma unroll
    for (int kk = 0; kk < 4; ++kk) {
        g.v[2 * kk]     = *(const float4*)(src + kk * 32);
        g.v[2 * kk + 1] = *(const float4*)(src + kk * 32 + 4);
    }
}

// Compute one 16-edge group: 8 h-tiles x 4 k-slices of mfma_f32_16x16x32_bf16.
// A operand = matrix tile from LDS (m = h), B operand = gathered edges (n = e).
// D: lane (q,c) holds h = nt*16 + q*4 + reg of edge c -> float4 stores.
__device__ inline void compute(const unsigned char* Mlds,
                               const unsigned short* list,
                               float* __restrict__ out, int e0, int n_g,
                               int base, int q, int c, const G& g) {
    bf16x8 bf[4];
#pragma unroll
    for (int kk = 0; kk < 4; ++kk) bf[kk] = pack8(g.v[2 * kk], g.v[2 * kk + 1]);

    const int  idx = base + c;
    const bool ok  = idx < n_g;
    float* dst = out + (size_t)(e0 + list[ok ? idx : 0]) * HIDDEN + q * 4;

#pragma unroll
    for (int nt = 0; nt < 8; ++nt) {
        const unsigned char* arow = Mlds + (size_t)(nt * 16 + c) * RS + q * 16;
        bf16x8 a0 = *(const bf16x8*)(arow);
        bf16x8 a1 = *(const bf16x8*)(arow + 64);
        bf16x8 a2 = *(const bf16x8*)(arow + 128);
        bf16x8 a3 = *(const bf16x8*)(arow + 192);
        f32x4 acc = {0.f, 0.f, 0.f, 0.f};
        acc = __builtin_amdgcn_mfma_f32_16x16x32_bf16(a0, bf[0], acc, 0, 0, 0);
        acc = __builtin_amdgcn_mfma_f32_16x16x32_bf16(a1, bf[1], acc, 0, 0, 0);
        acc = __builtin_amdgcn_mfma_f32_16x16x32_bf16(a2, bf[2], acc, 0, 0, 0);
        acc = __builtin_amdgcn_mfma_f32_16x16x32_bf16(a3, bf[3], acc, 0, 0, 0);
        if (ok) *(float4*)(dst + nt * 16) = *(const float4*)&acc;
    }
}

__global__ __launch_bounds__(256, 4) void matrix_message_kernel(
    const float* __restrict__ h_w,   // (E,128) f32
    const float* __restrict__ ef,    // (E,8)   f32 one-hot
    const float* __restrict__ M,     // (8,128,128) f32
    float*       __restrict__ out)   // (E,128) f32
{
    __shared__ unsigned short list[CHUNK];
    __shared__ int cnt;
    __shared__ __align__(16) unsigned char Mlds[128 * RS];

    const int tid  = threadIdx.x;
    const int w    = tid >> 6;
    const int lane = tid & 63;
    const int q    = lane >> 4;
    const int c    = lane & 15;
    const int k    = blockIdx.y;
    const int e0   = blockIdx.x * CHUNK;

    if (tid == 0) cnt = 0;
    __syncthreads();

    // Stage M_k -> LDS (bf16, 272B row stride). 2048 8-float chunks / 256 thr.
    const float* Mb = M + (size_t)k * (HIDDEN * HIDDEN);
#pragma unroll
    for (int i = 0; i < 8; ++i) {
        const int chunk = i * 256 + tid;          // 0..2047
        const int row = chunk >> 4, j = chunk & 15;
        const float4* s4 = (const float4*)(Mb + (size_t)row * HIDDEN + j * 8);
        float4 v0 = s4[0], v1 = s4[1];
        *(bf16x8*)(Mlds + (size_t)row * RS + j * 16) = pack8(v0, v1);
    }

    // Ballot-compaction scan of this chunk's one-hot column k.
#pragma unroll
    for (int t0 = 0; t0 < CHUNK; t0 += 256) {
        const int t = t0 + tid;
        const bool m = ef[(size_t)(e0 + t) * 8 + k] > 0.5f;
        const unsigned long long mask = __ballot(m);
        int base = 0;
        if (lane == 0) base = atomicAdd(&cnt, __popcll(mask));
        base = __shfl(base, 0);
        if (m) {
            const int off = __popcll(mask & ((1ull << lane) - 1ull));
            list[base + off] = (unsigned short)t;
        }
    }
    __syncthreads();   // LAST barrier: M staged + list complete

    const int n_g  = cnt;
    const int ng16 = (n_g + 15) >> 4;   // 16-edge groups
    if (w >= ng16) return;

    // Wave-private ping-pong pipeline over groups w, w+4, w+8, ...
    G A, B;
    int gi = w;
    gather(h_w, list, e0, n_g, gi * 16, q, c, A);
    while (true) {
        const int gn = gi + 4;
        const bool hasB = gn < ng16;
        if (hasB) gather(h_w, list, e0, n_g, gn * 16, q, c, B);
        compute(Mlds, list, out, e0, n_g, gi * 16, q, c, A);
        if (!hasB) break;
        gi = gn;

        const int gn2 = gi + 4;
        const bool hasA = gn2 < ng16;
        if (hasA) gather(h_w, list, e0, n_g, gn2 * 16, q, c, A);
        compute(Mlds, list, out, e0, n_g, gi * 16, q, c, B);
        if (!hasA) break;
        gi = gn2;
    }
}

extern "C" void kernel_launch(void* const* d_in, const int* in_sizes, int n_in,
                              void* d_out, int out_size, void* d_ws, size_t ws_size,
                              hipStream_t stream) {
    // d_in order: h_v (unused), h_w, edge_features, edge_matrices — all f32
    const float* h_w = (const float*)d_in[1];
    const float* ef  = (const float*)d_in[2];
    const float* M   = (const float*)d_in[3];
    float*       out = (float*)d_out;

    dim3 grid(NEDGES / CHUNK, 8, 1);   // 125 chunks x 8 types
    dim3 block(256, 1, 1);
    matrix_message_kernel<<<grid, block, 0, stream>>>(h_w, ef, M, out);
}

// Round 5
// 403.650 us; speedup vs baseline: 1.1719x; 1.1719x over previous
//
#include <hip/hip_runtime.h>
#include <hip/hip_bf16.h>

// messages[e,:] = edge_matrices[type(e)] @ h_w[e,:]
// Inputs (all FLOAT32): h_v (unused), h_w (E,128), edge_features (E,8) one-hot,
// edge_matrices (8,128,128). Output f32 (E,128).
//
// Round-5 design (round 3/4 died at container level before dispatch):
//   - M_k REGISTER-RESIDENT per wave (32x bf16x8 = 128 VGPR, loaded once):
//     removes the 32 per-group LDS A-reads that made round-3's LDS pipe
//     (672 cy/group) co-bottleneck with HBM (667 cy/group). Now 24 DS
//     ops/group (~288 cy) << HBM budget.
//   - Wave-autonomous main loop, ZERO barriers after setup. Each wave owns
//     16-edge groups (w, w+4, ...), computes all 128 h.
//   - Per-instruction memory granularity kept clean (round-1-proven):
//     gathers and stores are 4 rows x 256B contiguous per instruction via a
//     small wave-private LDS transpose buffer (lgkmcnt-ordered, no barrier).
//   - Depth-1 register prefetch (cur/nxt G sets, static names) hides HBM
//     gather latency under the previous group's transpose+MFMA+store.

#define NEDGES 320000
#define HIDDEN 128
#define CHUNK  2560            // 320000/2560 = 125 chunks
#define RS     272             // staging row stride bytes (16B aligned, conflict-light)

typedef __bf16 bf16x8 __attribute__((ext_vector_type(8)));
typedef float  f32x4  __attribute__((ext_vector_type(4)));

struct G { float4 v[8]; };     // one group's raw gather slice (per lane, 128 B)

__device__ inline bf16x8 pack8(const float4 v0, const float4 v1) {
    bf16x8 p;
    p[0] = (__bf16)v0.x; p[1] = (__bf16)v0.y; p[2] = (__bf16)v0.z; p[3] = (__bf16)v0.w;
    p[4] = (__bf16)v1.x; p[5] = (__bf16)v1.y; p[6] = (__bf16)v1.z; p[7] = (__bf16)v1.w;
    return p;
}

// Coalesced gather of group [gbase, gbase+16): lane (q,c) loads rows
// r = rb*4+q, floats [c*8, c*8+8). Per instruction: 4 rows x 256B contiguous.
__device__ inline void gather(const float* __restrict__ h_w,
                              const unsigned short* list, int e0, int n_g,
                              int gbase, int q, int c, G& g) {
#pragma unroll
    for (int rb = 0; rb < 4; ++rb) {
        int idx = gbase + rb * 4 + q;
        if (idx >= n_g) idx = 0;   // clamp; store side predicates
        const float* src = h_w + (size_t)(e0 + list[idx]) * HIDDEN + c * 8;
        g.v[2 * rb]     = *(const float4*)src;
        g.v[2 * rb + 1] = *(const float4*)(src + 4);
    }
}

// Pack + wave-private LDS stage: row r = rb*4+q gets bf16 elems [c*8, +8)
// at byte c*16 -> row r linear in d (elem d at byte 2d).
__device__ inline void stage(unsigned char* buf, int q, int c, const G& g) {
#pragma unroll
    for (int rb = 0; rb < 4; ++rb)
        *(bf16x8*)(buf + (rb * 4 + q) * RS + c * 16) = pack8(g.v[2 * rb], g.v[2 * rb + 1]);
}

// Read MFMA B-fragments: lane (q,c) = edge c, d-elems [kk*32+q*8, +8).
__device__ inline void load_bfr(const unsigned char* buf, int q, int c, bf16x8* bfr) {
#pragma unroll
    for (int kk = 0; kk < 4; ++kk)
        bfr[kk] = *(const bf16x8*)(buf + c * RS + kk * 64 + q * 16);
}

// 32 MFMA (8 h-tiles x 4 k-slices), A = register-resident M fragments.
// D transposed back through buf (wave-private; within-wave DS ordering makes
// the WAR on the just-read B region safe) -> 256B-contiguous stores.
// acc kept 4-wide (half at a time) to bound VGPR pressure.
__device__ inline void mfma_dstore(const bf16x8 (&m)[8][4], unsigned char* buf,
                                   const bf16x8* bfr, const unsigned short* list,
                                   float* __restrict__ out, int e0, int n_g,
                                   int gbase, int q, int c) {
#pragma unroll
    for (int half = 0; half < 2; ++half) {
        f32x4 acc[4];
#pragma unroll
        for (int nt = 0; nt < 4; ++nt) {
            f32x4 a = {0.f, 0.f, 0.f, 0.f};
#pragma unroll
            for (int kk = 0; kk < 4; ++kk)
                a = __builtin_amdgcn_mfma_f32_16x16x32_bf16(m[half * 4 + nt][kk], bfr[kk], a, 0, 0, 0);
            acc[nt] = a;   // D[h = (half*4+nt)*16 + q*4 + reg][edge c]
        }
        // Transpose: buffer row c (edge) holds h_local = nt*16+q*4+reg at
        // float offset h_local -> rows linear in h within this half.
#pragma unroll
        for (int nt = 0; nt < 4; ++nt)
            *(f32x4*)(buf + c * RS + nt * 64 + q * 16) = acc[nt];
        // Read back 4 rows x 256B per instruction -> coalesced stores.
#pragma unroll
        for (int rb = 0; rb < 4; ++rb) {
            const int r = rb * 4 + q;
            const int idx = gbase + r;
            f32x4 d = *(const f32x4*)(buf + r * RS + c * 16);
            if (idx < n_g) {
                float* dst = out + (size_t)(e0 + list[idx]) * HIDDEN + half * 64 + c * 4;
                *(float4*)dst = *(const float4*)&d;
            }
        }
    }
}

__global__ __launch_bounds__(256, 2) void matrix_message_kernel(
    const float* __restrict__ h_w,   // (E,128) f32
    const float* __restrict__ ef,    // (E,8)   f32 one-hot
    const float* __restrict__ M,     // (8,128,128) f32
    float*       __restrict__ out)   // (E,128) f32
{
    __shared__ unsigned short list[CHUNK];
    __shared__ int cnt;
    __shared__ __align__(16) unsigned char Stg[4][16 * RS];   // 17408 B

    const int tid  = threadIdx.x;
    const int w    = tid >> 6;
    const int lane = tid & 63;
    const int q    = lane >> 4;
    const int c    = lane & 15;
    const int k    = blockIdx.y;
    const int e0   = blockIdx.x * CHUNK;

    if (tid == 0) cnt = 0;
    __syncthreads();

    // M_k -> registers (per wave, all 128 h). A-frag layout (verified round 1):
    // A[m=c][slice j of (q,kk)] = M_k[h = nt*16 + c][d = kk*32 + q*8 + j].
    // One-time scattered read; M is 512 KB total -> L2/L3 resident.
    const float* Mb = M + (size_t)k * (HIDDEN * HIDDEN);
    bf16x8 m[8][4];
#pragma unroll
    for (int nt = 0; nt < 8; ++nt)
#pragma unroll
        for (int kk = 0; kk < 4; ++kk) {
            const float* src = Mb + (size_t)(nt * 16 + c) * HIDDEN + kk * 32 + q * 8;
            m[nt][kk] = pack8(*(const float4*)src, *(const float4*)(src + 4));
        }

    // Ballot-compaction scan of this chunk's one-hot column k.
#pragma unroll
    for (int t0 = 0; t0 < CHUNK; t0 += 256) {
        const int t = t0 + tid;
        const bool mt = ef[(size_t)(e0 + t) * 8 + k] > 0.5f;
        const unsigned long long mask = __ballot(mt);
        int base = 0;
        if (lane == 0) base = atomicAdd(&cnt, __popcll(mask));
        base = __shfl(base, 0);
        if (mt) {
            const int off = __popcll(mask & ((1ull << lane) - 1ull));
            list[base + off] = (unsigned short)t;
        }
    }
    __syncthreads();   // LAST barrier: list complete

    const int n_g  = cnt;
    const int ng16 = (n_g + 15) >> 4;
    if (w >= ng16) return;

    unsigned char* buf = Stg[w];

    G cur, nxt;
    int gi = w;
    gather(h_w, list, e0, n_g, gi * 16, q, c, cur);
    bool hasn = (gi + 4) < ng16;
    if (hasn) gather(h_w, list, e0, n_g, (gi + 4) * 16, q, c, nxt);

    bf16x8 bfr[4];
    for (;;) {
        stage(buf, q, c, cur);          // waits vmcnt on cur (issued >=1 group ago)
        load_bfr(buf, q, c, bfr);
        mfma_dstore(m, buf, bfr, list, out, e0, n_g, gi * 16, q, c);
        if (!hasn) break;
        gi += 4;
        cur = nxt;                      // 32 v_mov; waits nxt's vmcnt (old loads)
        hasn = (gi + 4) < ng16;
        if (hasn) gather(h_w, list, e0, n_g, (gi + 4) * 16, q, c, nxt);
    }
}

extern "C" void kernel_launch(void* const* d_in, const int* in_sizes, int n_in,
                              void* d_out, int out_size, void* d_ws, size_t ws_size,
                              hipStream_t stream) {
    // d_in order: h_v (unused), h_w, edge_features, edge_matrices — all f32
    const float* h_w = (const float*)d_in[1];
    const float* ef  = (const float*)d_in[2];
    const float* M   = (const float*)d_in[3];
    float*       out = (float*)d_out;

    dim3 grid(NEDGES / CHUNK, 8, 1);   // 125 chunks x 8 types
    dim3 block(256, 1, 1);
    matrix_message_kernel<<<grid, block, 0, stream>>>(h_w, ef, M, out);
}